// Round 1
// baseline (217.859 us; speedup 1.0000x reference)
//
#include <hip/hip_runtime.h>

// SpatialCrossAttention (BEVFormer) — fp32 baseline, 3 kernels:
//  A) vproj : value @ Wv + bv -> vhw[s][h][m][dh]
//  B) qproj : (query+query_pos) @ {Wo,Wa} + softmax -> off[n][64], attw[n][32]
//  C) attn  : bilinear sample + head-weighted sum + camera-masked mean + @Wp + residual

#define S_DIM 6
#define N_DIM 10000
#define C_DIM 128
#define M_DIM 3680
#define H_DIM 4
#define P_DIM 8
#define DH    32
#define HF    46
#define WF    80

#define VHW_FLOATS (S_DIM * H_DIM * M_DIM * DH)   // 2,826,240
#define OFF_FLOATS (N_DIM * 64)                   //   640,000
#define ATTW_FLOATS (N_DIM * 32)                  //   320,000

// ---------------------------------------------------------------- kernel A
__global__ __launch_bounds__(128) void vproj_kernel(
    const float* __restrict__ value,   // (S, M, 1, C)
    const float* __restrict__ Wv,      // (C, C)
    const float* __restrict__ bv,      // (C)
    float* __restrict__ vhw)           // (S, H, M, DH)
{
    const int row0 = blockIdx.x * 8;         // row = s*M + m
    const int t = threadIdx.x;               // 128 threads = one output column
    __shared__ float vs[8][C_DIM];

#pragma unroll
    for (int i = 0; i < 8; ++i)
        vs[i][t] = value[(size_t)(row0 + i) * C_DIM + t];
    __syncthreads();

    float acc[8];
#pragma unroll
    for (int i = 0; i < 8; ++i) acc[i] = 0.f;

    for (int k = 0; k < C_DIM; ++k) {
        const float w = Wv[k * C_DIM + t];
#pragma unroll
        for (int i = 0; i < 8; ++i) acc[i] = fmaf(vs[i][k], w, acc[i]);
    }
    const float b = bv[t];
    const int h = t >> 5, dh = t & 31;
#pragma unroll
    for (int i = 0; i < 8; ++i) {
        const int row = row0 + i;
        const int s = row / M_DIM;
        const int m = row - s * M_DIM;
        vhw[(((size_t)s * H_DIM + h) * M_DIM + m) * DH + dh] = acc[i] + b;
    }
}

// ---------------------------------------------------------------- kernel B
__global__ __launch_bounds__(128) void qproj_kernel(
    const float* __restrict__ query,
    const float* __restrict__ query_pos,
    const float* __restrict__ Wo, const float* __restrict__ bo,   // (C,64),(64)
    const float* __restrict__ Wa, const float* __restrict__ ba,   // (C,32),(32)
    float* __restrict__ off_out,    // (N,64)  layout (h,p,xy)
    float* __restrict__ attw_out)   // (N,32)  layout (h,p)
{
    const int n = blockIdx.x;
    const int t = threadIdx.x;   // 128
    __shared__ float qs[C_DIM];
    qs[t] = query[(size_t)n * C_DIM + t] + query_pos[(size_t)n * C_DIM + t];
    __syncthreads();

    if (t < 64) {
        float acc = 0.f;
        for (int k = 0; k < C_DIM; ++k) acc = fmaf(qs[k], Wo[k * 64 + t], acc);
        off_out[(size_t)n * 64 + t] = acc + bo[t];
    } else if (t < 96) {
        const int j = t - 64;    // lane 0..31 of wave 1
        float acc = 0.f;
        for (int k = 0; k < C_DIM; ++k) acc = fmaf(qs[k], Wa[k * 32 + j], acc);
        acc += ba[j];
        // softmax over groups of 8 (j = h*8 + p)
        float m = acc;
        for (int d = 1; d < 8; d <<= 1) m = fmaxf(m, __shfl_xor(m, d, 8));
        const float e = expf(acc - m);
        float sum = e;
        for (int d = 1; d < 8; d <<= 1) sum += __shfl_xor(sum, d, 8);
        attw_out[(size_t)n * 32 + j] = e / sum;
    }
}

// ---------------------------------------------------------------- kernel C
__global__ __launch_bounds__(128) void attn_kernel(
    const float* __restrict__ vhw,      // (S,H,M,DH)
    const float* __restrict__ off,      // (N,64)
    const float* __restrict__ attw,     // (N,32)
    const float* __restrict__ refpts,   // (S,1,N,4,2)
    const void* __restrict__ bev_mask,  // (S,1,N,4) bool/int32
    const void* __restrict__ sshapes,   // int probe
    const float* __restrict__ query,
    const float* __restrict__ Wp, const float* __restrict__ bp,
    float* __restrict__ out)            // (1,N,C)
{
    const int n = blockIdx.x;
    const int t = threadIdx.x;          // 128 = C
    const int h = t >> 5, dh = t & 31;

    __shared__ float s_off[64];
    __shared__ float s_attw[32];
    __shared__ float s_ref[S_DIM][4][2];
    __shared__ float s_slots[C_DIM];
    __shared__ int   s_mask[S_DIM];

    if (t < 64)       s_off[t]       = off[(size_t)n * 64 + t];
    else if (t < 96)  s_attw[t - 64] = attw[(size_t)n * 32 + (t - 64)];

    if (t < S_DIM * 8) {
        const int s = t >> 3, r = t & 7;  // r = d*2 + xy
        ((float*)s_ref)[t] = refpts[((size_t)s * N_DIM + n) * 8 + r];
    }
    if (t < S_DIM) {
        // detect harness integer canonicalization via spatial_shapes
        const int* ss32 = (const int*)sshapes;
        const bool i32mode = (ss32[1] == WF);
        int mk;
        if (i32mode) {
            const int* bm = (const int*)bev_mask + ((size_t)t * N_DIM + n) * 4;
            mk = (bm[0] | bm[1] | bm[2] | bm[3]) ? 1 : 0;
        } else {
            const unsigned char* bm =
                (const unsigned char*)bev_mask + ((size_t)t * N_DIM + n) * 4;
            mk = (bm[0] | bm[1] | bm[2] | bm[3]) ? 1 : 0;
        }
        s_mask[t] = mk;
    }
    __syncthreads();

    // per-point normalized offsets (same for all cameras) — reference-parity math
    float ox[P_DIM], oy[P_DIM], aw[P_DIM];
#pragma unroll
    for (int p = 0; p < P_DIM; ++p) {
        ox[p] = s_off[(h * P_DIM + p) * 2 + 0] / (float)WF;
        oy[p] = s_off[(h * P_DIM + p) * 2 + 1] / (float)HF;
        aw[p] = s_attw[h * P_DIM + p];
    }

    float acc = 0.f;
    int cnt = 0;
    for (int s = 0; s < S_DIM; ++s) {
        if (!s_mask[s]) continue;
        ++cnt;
        const float* vbase = vhw + ((size_t)s * H_DIM + h) * (M_DIM * DH);
#pragma unroll
        for (int p = 0; p < P_DIM; ++p) {
            const int d = p & 3;
            const float locx = s_ref[s][d][0] + ox[p];
            const float locy = s_ref[s][d][1] + oy[p];
            const float x = locx * (float)WF - 0.5f;
            const float y = locy * (float)HF - 0.5f;
            const float x0f = floorf(x), y0f = floorf(y);
            const float lx = x - x0f, ly = y - y0f;
            const int x0 = (int)x0f, y0 = (int)y0f;
            const float w = aw[p];
            const float w00 = (1.f - lx) * (1.f - ly) * w;
            const float w10 = lx * (1.f - ly) * w;
            const float w01 = (1.f - lx) * ly * w;
            const float w11 = lx * ly * w;
            const bool vx0 = (x0 >= 0) & (x0 < WF);
            const bool vx1 = (x0 >= -1) & (x0 < WF - 1);
            const bool vy0 = (y0 >= 0) & (y0 < HF);
            const bool vy1 = (y0 >= -1) & (y0 < HF - 1);
            if (vy0) {
                const int base = y0 * WF;
                if (vx0) acc += w00 * vbase[(size_t)(base + x0) * DH + dh];
                if (vx1) acc += w10 * vbase[(size_t)(base + x0 + 1) * DH + dh];
            }
            if (vy1) {
                const int base = (y0 + 1) * WF;
                if (vx0) acc += w01 * vbase[(size_t)(base + x0) * DH + dh];
                if (vx1) acc += w11 * vbase[(size_t)(base + x0 + 1) * DH + dh];
            }
        }
    }

    const float inv = 1.f / fmaxf((float)cnt, 1.f);
    s_slots[t] = acc * inv;
    __syncthreads();

    float o = 0.f;
    for (int k = 0; k < C_DIM; ++k) o = fmaf(s_slots[k], Wp[k * C_DIM + t], o);
    out[(size_t)n * C_DIM + t] = o + bp[t] + query[(size_t)n * C_DIM + t];
}

// ---------------------------------------------------------------- launch
extern "C" void kernel_launch(void* const* d_in, const int* in_sizes, int n_in,
                              void* d_out, int out_size, void* d_ws, size_t ws_size,
                              hipStream_t stream) {
    const float* query     = (const float*)d_in[0];
    // d_in[1] = key (unused by reference)
    const float* value     = (const float*)d_in[2];
    const float* query_pos = (const float*)d_in[3];
    const float* refpts    = (const float*)d_in[4];
    const float* Wv        = (const float*)d_in[5];
    const float* bv        = (const float*)d_in[6];
    const float* Wo        = (const float*)d_in[7];
    const float* bo        = (const float*)d_in[8];
    const float* Wa        = (const float*)d_in[9];
    const float* ba        = (const float*)d_in[10];
    const float* Wp        = (const float*)d_in[11];
    const float* bp        = (const float*)d_in[12];
    const void*  sshapes   = d_in[13];
    const void*  bev_mask  = d_in[14];

    float* ws   = (float*)d_ws;
    float* vhw  = ws;
    float* offb = ws + VHW_FLOATS;
    float* attw = ws + VHW_FLOATS + OFF_FLOATS;
    float* outp = (float*)d_out;

    hipLaunchKernelGGL(vproj_kernel, dim3((S_DIM * M_DIM) / 8), dim3(128), 0, stream,
                       value, Wv, bv, vhw);
    hipLaunchKernelGGL(qproj_kernel, dim3(N_DIM), dim3(128), 0, stream,
                       query, query_pos, Wo, bo, Wa, ba, offb, attw);
    hipLaunchKernelGGL(attn_kernel, dim3(N_DIM), dim3(128), 0, stream,
                       vhw, offb, attw, refpts, bev_mask, sshapes,
                       query, Wp, bp, outp);
}

// Round 2
// 120.777 us; speedup vs baseline: 1.8038x; 1.8038x over previous
//
#include <hip/hip_runtime.h>

// SpatialCrossAttention (BEVFormer) — fp32, 3 kernels:
//  A) vproj : value @ Wv + bv -> vhw[s][h][m][dh]
//  B) qproj : (query+query_pos) @ {Wo,Wa} + softmax -> off[n][64], attw[n][32]
//  C) attn  : phase1 per-(s,h,p) weights/offsets in LDS (deduped 32x),
//             phase2 branch-free batched gathers, phase3 @Wp + residual

#define S_DIM 6
#define N_DIM 10000
#define C_DIM 128
#define M_DIM 3680
#define H_DIM 4
#define P_DIM 8
#define DH    32
#define HF    46
#define WF    80

#define VHW_FLOATS (S_DIM * H_DIM * M_DIM * DH)   // 2,826,240
#define OFF_FLOATS (N_DIM * 64)
#define ATTW_FLOATS (N_DIM * 32)
#define NENT (S_DIM * H_DIM * P_DIM)              // 192

// ---------------------------------------------------------------- kernel A
__global__ __launch_bounds__(128) void vproj_kernel(
    const float* __restrict__ value,   // (S, M, 1, C)
    const float* __restrict__ Wv,      // (C, C)
    const float* __restrict__ bv,      // (C)
    float* __restrict__ vhw)           // (S, H, M, DH)
{
    const int row0 = blockIdx.x * 16;        // row = s*M + m
    const int t = threadIdx.x;               // 128 threads = one output column
    __shared__ float vs[16][C_DIM];

#pragma unroll
    for (int i = 0; i < 16; ++i)
        vs[i][t] = value[(size_t)(row0 + i) * C_DIM + t];
    __syncthreads();

    float acc[16];
#pragma unroll
    for (int i = 0; i < 16; ++i) acc[i] = 0.f;

    for (int k = 0; k < C_DIM; k += 4) {
        const float w0 = Wv[(k + 0) * C_DIM + t];
        const float w1 = Wv[(k + 1) * C_DIM + t];
        const float w2 = Wv[(k + 2) * C_DIM + t];
        const float w3 = Wv[(k + 3) * C_DIM + t];
#pragma unroll
        for (int i = 0; i < 16; ++i) {
            const float4 v = *(const float4*)&vs[i][k];
            acc[i] = fmaf(v.x, w0, acc[i]);
            acc[i] = fmaf(v.y, w1, acc[i]);
            acc[i] = fmaf(v.z, w2, acc[i]);
            acc[i] = fmaf(v.w, w3, acc[i]);
        }
    }
    const float b = bv[t];
    const int h = t >> 5, dh = t & 31;
#pragma unroll
    for (int i = 0; i < 16; ++i) {
        const int row = row0 + i;
        const int s = row / M_DIM;
        const int m = row - s * M_DIM;
        vhw[(((size_t)s * H_DIM + h) * M_DIM + m) * DH + dh] = acc[i] + b;
    }
}

// ---------------------------------------------------------------- kernel B
__global__ __launch_bounds__(128) void qproj_kernel(
    const float* __restrict__ query,
    const float* __restrict__ query_pos,
    const float* __restrict__ Wo, const float* __restrict__ bo,   // (C,64),(64)
    const float* __restrict__ Wa, const float* __restrict__ ba,   // (C,32),(32)
    float* __restrict__ off_out,    // (N,64)  layout (h,p,xy)
    float* __restrict__ attw_out)   // (N,32)  layout (h,p)
{
    const int n = blockIdx.x;
    const int t = threadIdx.x;   // 128
    __shared__ float qs[C_DIM];
    qs[t] = query[(size_t)n * C_DIM + t] + query_pos[(size_t)n * C_DIM + t];
    __syncthreads();

    if (t < 64) {
        float acc = 0.f;
        for (int k = 0; k < C_DIM; ++k) acc = fmaf(qs[k], Wo[k * 64 + t], acc);
        off_out[(size_t)n * 64 + t] = acc + bo[t];
    } else if (t < 96) {
        const int j = t - 64;    // lane 0..31 of wave 1
        float acc = 0.f;
        for (int k = 0; k < C_DIM; ++k) acc = fmaf(qs[k], Wa[k * 32 + j], acc);
        acc += ba[j];
        float m = acc;
        for (int d = 1; d < 8; d <<= 1) m = fmaxf(m, __shfl_xor(m, d, 8));
        const float e = expf(acc - m);
        float sum = e;
        for (int d = 1; d < 8; d <<= 1) sum += __shfl_xor(sum, d, 8);
        attw_out[(size_t)n * 32 + j] = e / sum;
    }
}

// ---------------------------------------------------------------- kernel C
__global__ __launch_bounds__(128) void attn_kernel(
    const float* __restrict__ vhw,      // (S,H,M,DH)
    const float* __restrict__ off,      // (N,64)
    const float* __restrict__ attw,     // (N,32)
    const float* __restrict__ refpts,   // (S,1,N,4,2)
    const void* __restrict__ bev_mask,  // (S,1,N,4) bool/int32
    const void* __restrict__ sshapes,   // int probe
    const float* __restrict__ query,
    const float* __restrict__ Wp, const float* __restrict__ bp,
    float* __restrict__ out)            // (1,N,C)
{
    const int n = blockIdx.x;
    const int t = threadIdx.x;          // 128 = C
    const int h = t >> 5, dh = t & 31;

    __shared__ float s_w[NENT][4];      // folded corner weights
    __shared__ int   s_o[NENT][4];      // clamped byte offsets into vhw
    __shared__ float s_slots[C_DIM];
    __shared__ int   s_mask[S_DIM];

    if (t < S_DIM) {
        const int* ss32 = (const int*)sshapes;
        const bool i32mode = (ss32[1] == WF);
        int mk;
        if (i32mode) {
            const int* bm = (const int*)bev_mask + ((size_t)t * N_DIM + n) * 4;
            mk = (bm[0] | bm[1] | bm[2] | bm[3]) ? 1 : 0;
        } else {
            const unsigned char* bm =
                (const unsigned char*)bev_mask + ((size_t)t * N_DIM + n) * 4;
            mk = (bm[0] | bm[1] | bm[2] | bm[3]) ? 1 : 0;
        }
        s_mask[t] = mk;
    }

    // ---- phase 1: per-(s,h,p) weights + offsets, computed once per block
    for (int e = t; e < NENT; e += 128) {
        const int s  = e >> 5;           // e / 32
        const int hp = e & 31;           // h*8 + p
        const int p  = hp & 7;
        const int eh = hp >> 3;
        const int d  = p & 3;

        const float aw = attw[(size_t)n * 32 + hp];
        const float offx = off[(size_t)n * 64 + hp * 2 + 0] / (float)WF;
        const float offy = off[(size_t)n * 64 + hp * 2 + 1] / (float)HF;
        const float refx = refpts[(((size_t)s * N_DIM + n) * 4 + d) * 2 + 0];
        const float refy = refpts[(((size_t)s * N_DIM + n) * 4 + d) * 2 + 1];

        const float x = (refx + offx) * (float)WF - 0.5f;
        const float y = (refy + offy) * (float)HF - 0.5f;
        const float x0f = floorf(x), y0f = floorf(y);
        const float lx = x - x0f, ly = y - y0f;
        const int x0 = (int)x0f, y0 = (int)y0f;
        const int x1 = x0 + 1, y1 = y0 + 1;

        const bool vx0 = (x0 >= 0) & (x0 < WF);
        const bool vx1 = (x1 >= 0) & (x1 < WF);
        const bool vy0 = (y0 >= 0) & (y0 < HF);
        const bool vy1 = (y1 >= 0) & (y1 < HF);

        const int cx0 = min(max(x0, 0), WF - 1);
        const int cx1 = min(max(x1, 0), WF - 1);
        const int cy0 = min(max(y0, 0), HF - 1);
        const int cy1 = min(max(y1, 0), HF - 1);

        const int base = (s * H_DIM + eh) * M_DIM;          // row index base
        const int r0 = (base + cy0 * WF) ;
        const int r1 = (base + cy1 * WF) ;
        s_o[e][0] = (r0 + cx0) * (DH * 4);
        s_o[e][1] = (r0 + cx1) * (DH * 4);
        s_o[e][2] = (r1 + cx0) * (DH * 4);
        s_o[e][3] = (r1 + cx1) * (DH * 4);

        const float wx0 = 1.f - lx, wy0 = 1.f - ly;
        s_w[e][0] = (vx0 & vy0) ? wx0 * wy0 * aw : 0.f;
        s_w[e][1] = (vx1 & vy0) ? lx  * wy0 * aw : 0.f;
        s_w[e][2] = (vx0 & vy1) ? wx0 * ly  * aw : 0.f;
        s_w[e][3] = (vx1 & vy1) ? lx  * ly  * aw : 0.f;
    }
    __syncthreads();

    // ---- phase 2: branch-free batched gather
    const char* vbytes = (const char*)vhw;
    const int dh4 = dh * 4;
    float acc = 0.f;
    int cnt = 0;
    for (int s = 0; s < S_DIM; ++s) {
        if (!s_mask[s]) continue;
        ++cnt;
        const int ebase = s * 32 + h * 8;
#pragma unroll
        for (int p = 0; p < P_DIM; ++p) {
            const float4 w = *(const float4*)s_w[ebase + p];
            const int4   o = *(const int4*)s_o[ebase + p];
            acc = fmaf(w.x, *(const float*)(vbytes + (o.x + dh4)), acc);
            acc = fmaf(w.y, *(const float*)(vbytes + (o.y + dh4)), acc);
            acc = fmaf(w.z, *(const float*)(vbytes + (o.z + dh4)), acc);
            acc = fmaf(w.w, *(const float*)(vbytes + (o.w + dh4)), acc);
        }
    }

    const float inv = 1.f / fmaxf((float)cnt, 1.f);
    s_slots[t] = acc * inv;
    __syncthreads();

    // ---- phase 3: out projection + bias + residual
    float o = 0.f;
    for (int k = 0; k < C_DIM; k += 4) {
        const float4 sv = *(const float4*)&s_slots[k];
        o = fmaf(sv.x, Wp[(k + 0) * C_DIM + t], o);
        o = fmaf(sv.y, Wp[(k + 1) * C_DIM + t], o);
        o = fmaf(sv.z, Wp[(k + 2) * C_DIM + t], o);
        o = fmaf(sv.w, Wp[(k + 3) * C_DIM + t], o);
    }
    out[(size_t)n * C_DIM + t] = o + bp[t] + query[(size_t)n * C_DIM + t];
}

// ---------------------------------------------------------------- launch
extern "C" void kernel_launch(void* const* d_in, const int* in_sizes, int n_in,
                              void* d_out, int out_size, void* d_ws, size_t ws_size,
                              hipStream_t stream) {
    const float* query     = (const float*)d_in[0];
    // d_in[1] = key (unused by reference)
    const float* value     = (const float*)d_in[2];
    const float* query_pos = (const float*)d_in[3];
    const float* refpts    = (const float*)d_in[4];
    const float* Wv        = (const float*)d_in[5];
    const float* bv        = (const float*)d_in[6];
    const float* Wo        = (const float*)d_in[7];
    const float* bo        = (const float*)d_in[8];
    const float* Wa        = (const float*)d_in[9];
    const float* ba        = (const float*)d_in[10];
    const float* Wp        = (const float*)d_in[11];
    const float* bp        = (const float*)d_in[12];
    const void*  sshapes   = d_in[13];
    const void*  bev_mask  = d_in[14];

    float* ws   = (float*)d_ws;
    float* vhw  = ws;
    float* offb = ws + VHW_FLOATS;
    float* attw = ws + VHW_FLOATS + OFF_FLOATS;
    float* outp = (float*)d_out;

    hipLaunchKernelGGL(vproj_kernel, dim3((S_DIM * M_DIM) / 16), dim3(128), 0, stream,
                       value, Wv, bv, vhw);
    hipLaunchKernelGGL(qproj_kernel, dim3(N_DIM), dim3(128), 0, stream,
                       query, query_pos, Wo, bo, Wa, ba, offb, attw);
    hipLaunchKernelGGL(attn_kernel, dim3(N_DIM), dim3(128), 0, stream,
                       vhw, offb, attw, refpts, bev_mask, sshapes,
                       query, Wp, bp, outp);
}

// Round 3
// 89.499 us; speedup vs baseline: 2.4342x; 1.3495x over previous
//
#include <hip/hip_runtime.h>

// SpatialCrossAttention (BEVFormer) — 2 kernels:
//  A) vproj : value @ Wv + bv -> vhw[s][h][m][dh] in bf16
//  B) attn  : fused qproj(off,attw,softmax) + per-(g,s,h,p) weight/offset
//             precompute + bf16 gather (G=4 queries/block) + @Wp + residual

#define S_DIM 6
#define N_DIM 10000
#define C_DIM 128
#define M_DIM 3680
#define H_DIM 4
#define P_DIM 8
#define DH    32
#define HF    46
#define WF    80

#define G_Q   4
#define NENT  (S_DIM * H_DIM * P_DIM)             // 192
#define VHW_SHORTS (S_DIM * H_DIM * M_DIM * DH)   // 2,826,240

__device__ __forceinline__ float bf2f(unsigned short u) {
    return __uint_as_float(((unsigned)u) << 16);
}
__device__ __forceinline__ unsigned short f2bf(float f) {
    unsigned b = __float_as_uint(f);
    b += 0x7FFFu + ((b >> 16) & 1u);   // RNE
    return (unsigned short)(b >> 16);
}

// ---------------------------------------------------------------- kernel A
__global__ __launch_bounds__(128) void vproj_kernel(
    const float* __restrict__ value,   // (S, M, 1, C)
    const float* __restrict__ Wv,      // (C, C)
    const float* __restrict__ bv,      // (C)
    unsigned short* __restrict__ vhw)  // (S, H, M, DH) bf16
{
    const int row0 = blockIdx.x * 16;        // row = s*M + m
    const int t = threadIdx.x;               // 128 threads = one output column
    __shared__ float vs[16][C_DIM];

#pragma unroll
    for (int i = 0; i < 16; ++i)
        vs[i][t] = value[(size_t)(row0 + i) * C_DIM + t];
    __syncthreads();

    float acc[16];
#pragma unroll
    for (int i = 0; i < 16; ++i) acc[i] = 0.f;

    for (int k = 0; k < C_DIM; k += 4) {
        const float w0 = Wv[(k + 0) * C_DIM + t];
        const float w1 = Wv[(k + 1) * C_DIM + t];
        const float w2 = Wv[(k + 2) * C_DIM + t];
        const float w3 = Wv[(k + 3) * C_DIM + t];
#pragma unroll
        for (int i = 0; i < 16; ++i) {
            const float4 v = *(const float4*)&vs[i][k];
            acc[i] = fmaf(v.x, w0, acc[i]);
            acc[i] = fmaf(v.y, w1, acc[i]);
            acc[i] = fmaf(v.z, w2, acc[i]);
            acc[i] = fmaf(v.w, w3, acc[i]);
        }
    }
    const float b = bv[t];
    const int h = t >> 5, dh = t & 31;
#pragma unroll
    for (int i = 0; i < 16; ++i) {
        const int row = row0 + i;
        const int s = row / M_DIM;
        const int m = row - s * M_DIM;
        vhw[(((size_t)s * H_DIM + h) * M_DIM + m) * DH + dh] = f2bf(acc[i] + b);
    }
}

// ---------------------------------------------------------------- kernel B
__global__ __launch_bounds__(256, 4) void attn_kernel(
    const unsigned short* __restrict__ vhw,   // (S,H,M,DH) bf16
    const float* __restrict__ query,
    const float* __restrict__ query_pos,
    const float* __restrict__ Wo, const float* __restrict__ bo,   // (C,64),(64)
    const float* __restrict__ Wa, const float* __restrict__ ba,   // (C,32),(32)
    const float* __restrict__ refpts,   // (S,1,N,4,2)
    const void* __restrict__ bev_mask,  // (S,1,N,4) bool/int32
    const void* __restrict__ sshapes,   // int probe
    const float* __restrict__ Wp, const float* __restrict__ bp,
    float* __restrict__ out)            // (1,N,C)
{
    const int n0 = blockIdx.x * G_Q;
    const int t = threadIdx.x;          // 256

    __shared__ float qs[G_Q][C_DIM];       // 2 KB
    __shared__ float s_offr[G_Q][64];      // 1 KB (raw offsets)
    __shared__ float s_ar[G_Q][32];        // raw attn logits
    __shared__ float s_attw[G_Q][32];
    __shared__ float s_w[G_Q][NENT][4];    // 12 KB folded corner weights
    __shared__ int   s_o[G_Q][NENT][4];    // 12 KB byte offsets into vhw
    __shared__ float s_slots[G_Q][C_DIM];  // 2 KB
    __shared__ int   s_mask[G_Q][S_DIM];
    __shared__ float s_inv[G_Q];

    // ---- phase 0: queries + masks
    for (int i = t; i < G_Q * C_DIM; i += 256) {
        const int g = i >> 7, c = i & 127;
        const size_t a = (size_t)(n0 + g) * C_DIM + c;
        qs[g][c] = query[a] + query_pos[a];
    }
    if (t < G_Q * S_DIM) {   // 24
        const int g = t / S_DIM, s = t - g * S_DIM;
        const int n = n0 + g;
        const int* ss32 = (const int*)sshapes;
        const bool i32mode = (ss32[1] == WF);
        int mk;
        if (i32mode) {
            const int* bm = (const int*)bev_mask + ((size_t)s * N_DIM + n) * 4;
            mk = (bm[0] | bm[1] | bm[2] | bm[3]) ? 1 : 0;
        } else {
            const unsigned char* bm =
                (const unsigned char*)bev_mask + ((size_t)s * N_DIM + n) * 4;
            mk = (bm[0] | bm[1] | bm[2] | bm[3]) ? 1 : 0;
        }
        s_mask[g][s] = mk;
    }
    __syncthreads();
    if (t < G_Q) {
        int c = 0;
#pragma unroll
        for (int s = 0; s < S_DIM; ++s) c += s_mask[t][s];
        s_inv[t] = 1.f / fmaxf((float)c, 1.f);
    }

    // ---- phase 1: fused qproj (wave-uniform branches)
    {   // offsets: all 256 threads, g = t>>6, j = t&63
        const int g = t >> 6, j = t & 63;
        float acc = 0.f;
        for (int k = 0; k < C_DIM; k += 4) {
            const float4 q4 = *(const float4*)&qs[g][k];
            acc = fmaf(q4.x, Wo[(k + 0) * 64 + j], acc);
            acc = fmaf(q4.y, Wo[(k + 1) * 64 + j], acc);
            acc = fmaf(q4.z, Wo[(k + 2) * 64 + j], acc);
            acc = fmaf(q4.w, Wo[(k + 3) * 64 + j], acc);
        }
        s_offr[g][j] = acc + bo[j];
    }
    if (t < G_Q * 32) {   // attn logits: g = t>>5, jj = t&31
        const int g = t >> 5, jj = t & 31;
        float acc = 0.f;
        for (int k = 0; k < C_DIM; k += 4) {
            const float4 q4 = *(const float4*)&qs[g][k];
            acc = fmaf(q4.x, Wa[(k + 0) * 32 + jj], acc);
            acc = fmaf(q4.y, Wa[(k + 1) * 32 + jj], acc);
            acc = fmaf(q4.z, Wa[(k + 2) * 32 + jj], acc);
            acc = fmaf(q4.w, Wa[(k + 3) * 32 + jj], acc);
        }
        s_ar[g][jj] = acc + ba[jj];
    }
    __syncthreads();
    if (t < G_Q * 32) {   // softmax over groups of 8, lanes aligned in-wave
        const int g = t >> 5, hp = t & 31;
        const float v = s_ar[g][hp];
        float m = v;
        for (int d = 1; d < 8; d <<= 1) m = fmaxf(m, __shfl_xor(m, d, 8));
        const float e = expf(v - m);
        float sum = e;
        for (int d = 1; d < 8; d <<= 1) sum += __shfl_xor(sum, d, 8);
        s_attw[g][hp] = e / sum;
    }
    __syncthreads();

    // ---- phase 1b: per-(g,s,h,p) weights + byte offsets (768 entries)
    for (int i = t; i < G_Q * NENT; i += 256) {
        const int g = i / NENT, e = i - g * NENT;
        const int s = e >> 5, hp = e & 31;
        const int p = hp & 7, eh = hp >> 3, d = p & 3;
        const int n = n0 + g;

        const float aw = s_attw[g][hp];
        const float offx = s_offr[g][hp * 2 + 0] / (float)WF;
        const float offy = s_offr[g][hp * 2 + 1] / (float)HF;
        const float refx = refpts[(((size_t)s * N_DIM + n) * 4 + d) * 2 + 0];
        const float refy = refpts[(((size_t)s * N_DIM + n) * 4 + d) * 2 + 1];

        const float x = (refx + offx) * (float)WF - 0.5f;
        const float y = (refy + offy) * (float)HF - 0.5f;
        const float x0f = floorf(x), y0f = floorf(y);
        const float lx = x - x0f, ly = y - y0f;
        const int x0 = (int)x0f, y0 = (int)y0f;
        const int x1 = x0 + 1, y1 = y0 + 1;

        const bool vx0 = (x0 >= 0) & (x0 < WF);
        const bool vx1 = (x1 >= 0) & (x1 < WF);
        const bool vy0 = (y0 >= 0) & (y0 < HF);
        const bool vy1 = (y1 >= 0) & (y1 < HF);

        const int cx0 = min(max(x0, 0), WF - 1);
        const int cx1 = min(max(x1, 0), WF - 1);
        const int cy0 = min(max(y0, 0), HF - 1);
        const int cy1 = min(max(y1, 0), HF - 1);

        const int base = (s * H_DIM + eh) * M_DIM;
        const int r0 = base + cy0 * WF;
        const int r1 = base + cy1 * WF;
        s_o[g][e][0] = (r0 + cx0) * (DH * 2);   // bf16 rows: 64 B/pixel
        s_o[g][e][1] = (r0 + cx1) * (DH * 2);
        s_o[g][e][2] = (r1 + cx0) * (DH * 2);
        s_o[g][e][3] = (r1 + cx1) * (DH * 2);

        const float wx0 = 1.f - lx, wy0 = 1.f - ly;
        s_w[g][e][0] = (vx0 & vy0) ? wx0 * wy0 * aw : 0.f;
        s_w[g][e][1] = (vx1 & vy0) ? lx  * wy0 * aw : 0.f;
        s_w[g][e][2] = (vx0 & vy1) ? wx0 * ly  * aw : 0.f;
        s_w[g][e][3] = (vx1 & vy1) ? lx  * ly  * aw : 0.f;
    }
    __syncthreads();

    // ---- phase 2: gather, 2 passes x 2 queries, 16-deep load batching
    {
        const char* vb = (const char*)vhw;
        const int local = t & 127, qsel = t >> 7;
        const int h = local >> 5, dh2 = (local & 31) * 2;
#pragma unroll
        for (int gp = 0; gp < 2; ++gp) {
            const int g = gp * 2 + qsel;
            float acc = 0.f;
            for (int s = 0; s < S_DIM; ++s) {
                if (!s_mask[g][s]) continue;
                const int eb = s * 32 + h * 8;
#pragma unroll
                for (int pg = 0; pg < 2; ++pg) {
                    unsigned short r[16];
#pragma unroll
                    for (int p = 0; p < 4; ++p) {
                        const int4 o = *(const int4*)s_o[g][eb + pg * 4 + p];
                        r[p * 4 + 0] = *(const unsigned short*)(vb + (o.x + dh2));
                        r[p * 4 + 1] = *(const unsigned short*)(vb + (o.y + dh2));
                        r[p * 4 + 2] = *(const unsigned short*)(vb + (o.z + dh2));
                        r[p * 4 + 3] = *(const unsigned short*)(vb + (o.w + dh2));
                    }
#pragma unroll
                    for (int p = 0; p < 4; ++p) {
                        const float4 w = *(const float4*)s_w[g][eb + pg * 4 + p];
                        acc = fmaf(w.x, bf2f(r[p * 4 + 0]), acc);
                        acc = fmaf(w.y, bf2f(r[p * 4 + 1]), acc);
                        acc = fmaf(w.z, bf2f(r[p * 4 + 2]), acc);
                        acc = fmaf(w.w, bf2f(r[p * 4 + 3]), acc);
                    }
                }
            }
            s_slots[g][local] = acc * s_inv[g];
        }
    }
    __syncthreads();

    // ---- phase 3: out projection + bias + residual (Wp read 2x/block)
    {
        const int c = t & 127, half = t >> 7;
        const int g0 = half * 2;
        float a0 = 0.f, a1 = 0.f;
        for (int k = 0; k < C_DIM; k += 4) {
            const float4 s0 = *(const float4*)&s_slots[g0][k];
            const float4 s1 = *(const float4*)&s_slots[g0 + 1][k];
            const float w0 = Wp[(k + 0) * C_DIM + c];
            const float w1 = Wp[(k + 1) * C_DIM + c];
            const float w2 = Wp[(k + 2) * C_DIM + c];
            const float w3 = Wp[(k + 3) * C_DIM + c];
            a0 = fmaf(s0.x, w0, a0); a1 = fmaf(s1.x, w0, a1);
            a0 = fmaf(s0.y, w1, a0); a1 = fmaf(s1.y, w1, a1);
            a0 = fmaf(s0.z, w2, a0); a1 = fmaf(s1.z, w2, a1);
            a0 = fmaf(s0.w, w3, a0); a1 = fmaf(s1.w, w3, a1);
        }
        const int na = n0 + g0;
        const float bb = bp[c];
        out[(size_t)na * C_DIM + c]       = a0 + bb + query[(size_t)na * C_DIM + c];
        out[(size_t)(na + 1) * C_DIM + c] = a1 + bb + query[(size_t)(na + 1) * C_DIM + c];
    }
}

// ---------------------------------------------------------------- launch
extern "C" void kernel_launch(void* const* d_in, const int* in_sizes, int n_in,
                              void* d_out, int out_size, void* d_ws, size_t ws_size,
                              hipStream_t stream) {
    const float* query     = (const float*)d_in[0];
    // d_in[1] = key (unused by reference)
    const float* value     = (const float*)d_in[2];
    const float* query_pos = (const float*)d_in[3];
    const float* refpts    = (const float*)d_in[4];
    const float* Wv        = (const float*)d_in[5];
    const float* bv        = (const float*)d_in[6];
    const float* Wo        = (const float*)d_in[7];
    const float* bo        = (const float*)d_in[8];
    const float* Wa        = (const float*)d_in[9];
    const float* ba        = (const float*)d_in[10];
    const float* Wp        = (const float*)d_in[11];
    const float* bp        = (const float*)d_in[12];
    const void*  sshapes   = d_in[13];
    const void*  bev_mask  = d_in[14];

    unsigned short* vhw = (unsigned short*)d_ws;
    float* outp = (float*)d_out;

    hipLaunchKernelGGL(vproj_kernel, dim3((S_DIM * M_DIM) / 16), dim3(128), 0, stream,
                       value, Wv, bv, vhw);
    hipLaunchKernelGGL(attn_kernel, dim3(N_DIM / G_Q), dim3(256), 0, stream,
                       vhw, query, query_pos, Wo, bo, Wa, ba,
                       refpts, bev_mask, sshapes, Wp, bp, outp);
}

// Round 5
// 84.492 us; speedup vs baseline: 2.5785x; 1.0593x over previous
//
#include <hip/hip_runtime.h>

// SpatialCrossAttention (BEVFormer) — 2 kernels:
//  A) vproj : value @ Wv + bv -> vhw[s][h][m][dh] in bf16
//  B) attn  : fused qproj + per-(g,s,p,h) weight/offset precompute +
//             dword-pair bf16 gather (wave = 1 query, 2 dh per lane) + @Wp + residual

#define S_DIM 6
#define N_DIM 10000
#define C_DIM 128
#define M_DIM 3680
#define H_DIM 4
#define P_DIM 8
#define DH    32
#define HF    46
#define WF    80

#define G_Q   4
#define NENT  (S_DIM * P_DIM * H_DIM)             // 192
#define VHW_SHORTS (S_DIM * H_DIM * M_DIM * DH)   // 2,826,240

__device__ __forceinline__ float bfl(unsigned u) {   // low bf16 -> f32
    return __uint_as_float(u << 16);
}
__device__ __forceinline__ float bfh(unsigned u) {   // high bf16 -> f32
    return __uint_as_float(u & 0xffff0000u);
}
__device__ __forceinline__ unsigned short f2bf(float f) {
    unsigned b = __float_as_uint(f);
    b += 0x7FFFu + ((b >> 16) & 1u);   // RNE
    return (unsigned short)(b >> 16);
}

// ---------------------------------------------------------------- kernel A
__global__ __launch_bounds__(128) void vproj_kernel(
    const float* __restrict__ value,   // (S, M, 1, C)
    const float* __restrict__ Wv,      // (C, C)
    const float* __restrict__ bv,      // (C)
    unsigned short* __restrict__ vhw)  // (S, H, M, DH) bf16
{
    const int row0 = blockIdx.x * 16;        // row = s*M + m
    const int t = threadIdx.x;               // 128 threads = one output column
    __shared__ float vs[16][C_DIM];

#pragma unroll
    for (int i = 0; i < 16; ++i)
        vs[i][t] = value[(size_t)(row0 + i) * C_DIM + t];
    __syncthreads();

    float acc[16];
#pragma unroll
    for (int i = 0; i < 16; ++i) acc[i] = 0.f;

    for (int k = 0; k < C_DIM; k += 4) {
        const float w0 = Wv[(k + 0) * C_DIM + t];
        const float w1 = Wv[(k + 1) * C_DIM + t];
        const float w2 = Wv[(k + 2) * C_DIM + t];
        const float w3 = Wv[(k + 3) * C_DIM + t];
#pragma unroll
        for (int i = 0; i < 16; ++i) {
            const float4 v = *(const float4*)&vs[i][k];
            acc[i] = fmaf(v.x, w0, acc[i]);
            acc[i] = fmaf(v.y, w1, acc[i]);
            acc[i] = fmaf(v.z, w2, acc[i]);
            acc[i] = fmaf(v.w, w3, acc[i]);
        }
    }
    const float b = bv[t];
    const int h = t >> 5, dh = t & 31;
#pragma unroll
    for (int i = 0; i < 16; ++i) {
        const int row = row0 + i;
        const int s = row / M_DIM;
        const int m = row - s * M_DIM;
        vhw[(((size_t)s * H_DIM + h) * M_DIM + m) * DH + dh] = f2bf(acc[i] + b);
    }
}

// ---------------------------------------------------------------- kernel B
__global__ __launch_bounds__(256, 4) void attn_kernel(
    const unsigned short* __restrict__ vhw,   // (S,H,M,DH) bf16
    const float* __restrict__ query,
    const float* __restrict__ query_pos,
    const float* __restrict__ Wo, const float* __restrict__ bo,   // (C,64),(64)
    const float* __restrict__ Wa, const float* __restrict__ ba,   // (C,32),(32)
    const float* __restrict__ refpts,   // (S,1,N,4,2)
    const void* __restrict__ bev_mask,  // (S,1,N,4) bool/int32
    const void* __restrict__ sshapes,   // int probe
    const float* __restrict__ Wp, const float* __restrict__ bp,
    float* __restrict__ out)            // (1,N,C)
{
    const int n0 = blockIdx.x * G_Q;
    const int t = threadIdx.x;          // 256

    __shared__ float  qs[G_Q][C_DIM];                    // 2 KB
    __shared__ float  s_offr[G_Q][64];                   // 1 KB
    __shared__ float  s_ar[G_Q][32];
    __shared__ float  s_attw[G_Q][32];
    __shared__ int4   s_o[G_Q][S_DIM][P_DIM][H_DIM];     // 12 KB  [g][s][p][h]
    __shared__ float4 s_w[G_Q][S_DIM][P_DIM][H_DIM];     // 12 KB
    __shared__ float  s_slots[G_Q][C_DIM];               // 2 KB
    __shared__ int    s_mask[G_Q][S_DIM];
    __shared__ float  s_inv[G_Q];

    // ---- phase 0: queries + masks
    for (int i = t; i < G_Q * C_DIM; i += 256) {
        const int g = i >> 7, c = i & 127;
        const size_t a = (size_t)(n0 + g) * C_DIM + c;
        qs[g][c] = query[a] + query_pos[a];
    }
    if (t < G_Q * S_DIM) {   // 24
        const int g = t / S_DIM, s = t - g * S_DIM;
        const int n = n0 + g;
        const int* ss32 = (const int*)sshapes;
        const bool i32mode = (ss32[1] == WF);
        int mk;
        if (i32mode) {
            const int* bm = (const int*)bev_mask + ((size_t)s * N_DIM + n) * 4;
            mk = (bm[0] | bm[1] | bm[2] | bm[3]) ? 1 : 0;
        } else {
            const unsigned char* bm =
                (const unsigned char*)bev_mask + ((size_t)s * N_DIM + n) * 4;
            mk = (bm[0] | bm[1] | bm[2] | bm[3]) ? 1 : 0;
        }
        s_mask[g][s] = mk;
    }
    __syncthreads();
    if (t < G_Q) {
        int c = 0;
#pragma unroll
        for (int s = 0; s < S_DIM; ++s) c += s_mask[t][s];
        s_inv[t] = 1.f / fmaxf((float)c, 1.f);
    }

    // ---- phase 1: fused qproj
    {   // offsets: all 256 threads, g = t>>6, j = t&63
        const int g = t >> 6, j = t & 63;
        float acc = 0.f;
        for (int k = 0; k < C_DIM; k += 4) {
            const float4 q4 = *(const float4*)&qs[g][k];
            acc = fmaf(q4.x, Wo[(k + 0) * 64 + j], acc);
            acc = fmaf(q4.y, Wo[(k + 1) * 64 + j], acc);
            acc = fmaf(q4.z, Wo[(k + 2) * 64 + j], acc);
            acc = fmaf(q4.w, Wo[(k + 3) * 64 + j], acc);
        }
        s_offr[g][j] = acc + bo[j];
    }
    if (t < G_Q * 32) {   // attn logits: g = t>>5, jj = t&31
        const int g = t >> 5, jj = t & 31;
        float acc = 0.f;
        for (int k = 0; k < C_DIM; k += 4) {
            const float4 q4 = *(const float4*)&qs[g][k];
            acc = fmaf(q4.x, Wa[(k + 0) * 32 + jj], acc);
            acc = fmaf(q4.y, Wa[(k + 1) * 32 + jj], acc);
            acc = fmaf(q4.z, Wa[(k + 2) * 32 + jj], acc);
            acc = fmaf(q4.w, Wa[(k + 3) * 32 + jj], acc);
        }
        s_ar[g][jj] = acc + ba[jj];
    }
    __syncthreads();
    if (t < G_Q * 32) {   // softmax over groups of 8
        const int g = t >> 5, hp = t & 31;
        const float v = s_ar[g][hp];
        float m = v;
        for (int d = 1; d < 8; d <<= 1) m = fmaxf(m, __shfl_xor(m, d, 8));
        const float e = expf(v - m);
        float sum = e;
        for (int d = 1; d < 8; d <<= 1) sum += __shfl_xor(sum, d, 8);
        s_attw[g][hp] = e / sum;
    }
    __syncthreads();

    // ---- phase 1b: per-(g,s,p,h) weights + byte offsets (768 entries)
    for (int i = t; i < G_Q * NENT; i += 256) {
        const int g = i / NENT;
        const int e = i - g * NENT;      // e in [0,192)
        const int s = e >> 5;
        const int rem = e & 31;          // p*4 + h
        const int p = rem >> 2, h = rem & 3;
        const int hp = h * P_DIM + p;
        const int d = p & 3;
        const int n = n0 + g;

        const float aw = s_attw[g][hp];
        const float offx = s_offr[g][hp * 2 + 0] / (float)WF;
        const float offy = s_offr[g][hp * 2 + 1] / (float)HF;
        const float refx = refpts[(((size_t)s * N_DIM + n) * 4 + d) * 2 + 0];
        const float refy = refpts[(((size_t)s * N_DIM + n) * 4 + d) * 2 + 1];

        const float x = (refx + offx) * (float)WF - 0.5f;
        const float y = (refy + offy) * (float)HF - 0.5f;
        const float x0f = floorf(x), y0f = floorf(y);
        const float lx = x - x0f, ly = y - y0f;
        const int x0 = (int)x0f, y0 = (int)y0f;
        const int x1 = x0 + 1, y1 = y0 + 1;

        const bool vx0 = (x0 >= 0) & (x0 < WF);
        const bool vx1 = (x1 >= 0) & (x1 < WF);
        const bool vy0 = (y0 >= 0) & (y0 < HF);
        const bool vy1 = (y1 >= 0) & (y1 < HF);

        const int cx0 = min(max(x0, 0), WF - 1);
        const int cx1 = min(max(x1, 0), WF - 1);
        const int cy0 = min(max(y0, 0), HF - 1);
        const int cy1 = min(max(y1, 0), HF - 1);

        const int base = (s * H_DIM + h) * M_DIM;
        const int r0 = base + cy0 * WF;
        const int r1 = base + cy1 * WF;
        s_o[g][s][p][h] = make_int4((r0 + cx0) * (DH * 2),
                                    (r0 + cx1) * (DH * 2),
                                    (r1 + cx0) * (DH * 2),
                                    (r1 + cx1) * (DH * 2));

        const float wx0 = 1.f - lx, wy0 = 1.f - ly;
        s_w[g][s][p][h] = make_float4((vx0 & vy0) ? wx0 * wy0 * aw : 0.f,
                                      (vx1 & vy0) ? lx  * wy0 * aw : 0.f,
                                      (vx0 & vy1) ? wx0 * ly  * aw : 0.f,
                                      (vx1 & vy1) ? lx  * ly  * aw : 0.f);
    }
    __syncthreads();

    // ---- phase 2: gather — wave = 1 query, 16 lanes/head, 2 dh per lane
    {
        const char* vb = (const char*)vhw;
        const int g = t >> 6;
        const int lane = t & 63;
        const int h = lane >> 4;
        const int dhp4 = (lane & 15) * 4;   // byte offset of the dh pair
        float accx = 0.f, accy = 0.f;

        for (int s = 0; s < S_DIM; ++s) {
            if (!s_mask[g][s]) continue;
#pragma unroll
            for (int pg = 0; pg < 4; ++pg) {   // 2 points per batch
                const int4 o0 = s_o[g][s][pg * 2 + 0][h];
                const int4 o1 = s_o[g][s][pg * 2 + 1][h];
                unsigned u0 = *(const unsigned*)(vb + (o0.x + dhp4));
                unsigned u1 = *(const unsigned*)(vb + (o0.y + dhp4));
                unsigned u2 = *(const unsigned*)(vb + (o0.z + dhp4));
                unsigned u3 = *(const unsigned*)(vb + (o0.w + dhp4));
                unsigned u4 = *(const unsigned*)(vb + (o1.x + dhp4));
                unsigned u5 = *(const unsigned*)(vb + (o1.y + dhp4));
                unsigned u6 = *(const unsigned*)(vb + (o1.z + dhp4));
                unsigned u7 = *(const unsigned*)(vb + (o1.w + dhp4));
                const float4 w0 = s_w[g][s][pg * 2 + 0][h];
                const float4 w1 = s_w[g][s][pg * 2 + 1][h];
                accx = fmaf(w0.x, bfl(u0), accx); accy = fmaf(w0.x, bfh(u0), accy);
                accx = fmaf(w0.y, bfl(u1), accx); accy = fmaf(w0.y, bfh(u1), accy);
                accx = fmaf(w0.z, bfl(u2), accx); accy = fmaf(w0.z, bfh(u2), accy);
                accx = fmaf(w0.w, bfl(u3), accx); accy = fmaf(w0.w, bfh(u3), accy);
                accx = fmaf(w1.x, bfl(u4), accx); accy = fmaf(w1.x, bfh(u4), accy);
                accx = fmaf(w1.y, bfl(u5), accx); accy = fmaf(w1.y, bfh(u5), accy);
                accx = fmaf(w1.z, bfl(u6), accx); accy = fmaf(w1.z, bfh(u6), accy);
                accx = fmaf(w1.w, bfl(u7), accx); accy = fmaf(w1.w, bfh(u7), accy);
            }
        }
        const float inv = s_inv[g];
        *(float2*)&s_slots[g][h * 32 + (lane & 15) * 2] =
            make_float2(accx * inv, accy * inv);
    }
    __syncthreads();

    // ---- phase 3: out projection + bias + residual (Wp read 2x/block)
    {
        const int c = t & 127, half = t >> 7;
        const int g0 = half * 2;
        float a0 = 0.f, a1 = 0.f;
        for (int k = 0; k < C_DIM; k += 4) {
            const float4 s0 = *(const float4*)&s_slots[g0][k];
            const float4 s1 = *(const float4*)&s_slots[g0 + 1][k];
            const float w0 = Wp[(k + 0) * C_DIM + c];
            const float w1 = Wp[(k + 1) * C_DIM + c];
            const float w2 = Wp[(k + 2) * C_DIM + c];
            const float w3 = Wp[(k + 3) * C_DIM + c];
            a0 = fmaf(s0.x, w0, a0); a1 = fmaf(s1.x, w0, a1);
            a0 = fmaf(s0.y, w1, a0); a1 = fmaf(s1.y, w1, a1);
            a0 = fmaf(s0.z, w2, a0); a1 = fmaf(s1.z, w2, a1);
            a0 = fmaf(s0.w, w3, a0); a1 = fmaf(s1.w, w3, a1);
        }
        const int na = n0 + g0;
        const float bb = bp[c];
        out[(size_t)na * C_DIM + c]       = a0 + bb + query[(size_t)na * C_DIM + c];
        out[(size_t)(na + 1) * C_DIM + c] = a1 + bb + query[(size_t)(na + 1) * C_DIM + c];
    }
}

// ---------------------------------------------------------------- launch
extern "C" void kernel_launch(void* const* d_in, const int* in_sizes, int n_in,
                              void* d_out, int out_size, void* d_ws, size_t ws_size,
                              hipStream_t stream) {
    const float* query     = (const float*)d_in[0];
    // d_in[1] = key (unused by reference)
    const float* value     = (const float*)d_in[2];
    const float* query_pos = (const float*)d_in[3];
    const float* refpts    = (const float*)d_in[4];
    const float* Wv        = (const float*)d_in[5];
    const float* bv        = (const float*)d_in[6];
    const float* Wo        = (const float*)d_in[7];
    const float* bo        = (const float*)d_in[8];
    const float* Wa        = (const float*)d_in[9];
    const float* ba        = (const float*)d_in[10];
    const float* Wp        = (const float*)d_in[11];
    const float* bp        = (const float*)d_in[12];
    const void*  sshapes   = d_in[13];
    const void*  bev_mask  = d_in[14];

    unsigned short* vhw = (unsigned short*)d_ws;
    float* outp = (float*)d_out;

    hipLaunchKernelGGL(vproj_kernel, dim3((S_DIM * M_DIM) / 16), dim3(128), 0, stream,
                       value, Wv, bv, vhw);
    hipLaunchKernelGGL(attn_kernel, dim3(N_DIM / G_Q), dim3(256), 0, stream,
                       vhw, query, query_pos, Wo, bo, Wa, ba,
                       refpts, bev_mask, sshapes, Wp, bp, outp);
}